// Round 9
// baseline (257.292 us; speedup 1.0000x reference)
//
#include <hip/hip_runtime.h>

constexpr int N_CLASSES = 1000;   // 250 float4 per label row
constexpr int EMBED     = 1024;   // 256 float4 per row; 4 float4 per lane

typedef float floatx4 __attribute__((ext_vector_type(4)));

__device__ __forceinline__ floatx4 ntload(const floatx4* p) {
    return __builtin_nontemporal_load(p);
}

// ---------- Kernel A: labels -> cls_buf. Pure stream, zero chains. ----------
// Block per row; thread t<250 checks 4 classes; exactly one thread stores.
__global__ __launch_bounds__(256) void class_scan_kernel(
    const float* __restrict__ labels,
    int* __restrict__ cls_buf)
{
    const int row = blockIdx.x;
    const int t   = threadIdx.x;
    if (t < N_CLASSES / 4) {
        const floatx4* lrow = (const floatx4*)(labels + (size_t)row * N_CLASSES);
        floatx4 v = ntload(lrow + t);
        if (v.x != 0.f || v.y != 0.f || v.z != 0.f || v.w != 0.f) {
            int c = 4 * t;
            if      (v.y != 0.f) c += 1;
            else if (v.z != 0.f) c += 2;
            else if (v.w != 0.f) c += 3;
            cls_buf[row] = c;
        }
    }
}

// ---------- Kernel B: features + proto gather + dots. No intra-row chain. ---
// Wave per row, 4 rows/wave grid-stride. cls is a wave-uniform scalar load;
// feature stream (nt) and proto gather (cached) issue together, 8 independent
// 16B loads per lane per row. Low VGPR (~50) -> 8 waves/SIMD.
__global__ void angular_dots_kernel(
    const float* __restrict__ features,
    const float* __restrict__ mean_class,
    const int* __restrict__ cls_buf,
    float* __restrict__ partials,
    int n_rows)
{
    const int tid  = threadIdx.x;
    const int lane = tid & 63;
    const int wave = tid >> 6;
    const int wave_id = (blockIdx.x * blockDim.x + tid) >> 6;
    const int n_waves = (gridDim.x * blockDim.x) >> 6;

    float acc = 0.0f;

    for (int r = wave_id; r < n_rows; r += n_waves) {
        const int cls = cls_buf[r];   // r wave-uniform -> scalar load

        const floatx4* frow = (const floatx4*)(features + (size_t)r * EMBED);
        const floatx4* prow = (const floatx4*)(mean_class + (size_t)cls * EMBED);

        // 8 independent loads, no ordering dependence:
        floatx4 f0 = ntload(frow + lane);
        floatx4 f1 = ntload(frow + lane + 64);
        floatx4 f2 = ntload(frow + lane + 128);
        floatx4 f3 = ntload(frow + lane + 192);
        floatx4 p0 = prow[lane];
        floatx4 p1 = prow[lane + 64];
        floatx4 p2 = prow[lane + 128];
        floatx4 p3 = prow[lane + 192];

        float ff = 0.f, pp = 0.f, fp = 0.f;
        #define DOT3(F, P) \
            ff += F.x*F.x + F.y*F.y + F.z*F.z + F.w*F.w; \
            pp += P.x*P.x + P.y*P.y + P.z*P.z + P.w*P.w; \
            fp += F.x*P.x + F.y*P.y + F.z*P.z + F.w*P.w;
        DOT3(f0, p0) DOT3(f1, p1) DOT3(f2, p2) DOT3(f3, p3)
        #undef DOT3

        #pragma unroll
        for (int msk = 1; msk < 64; msk <<= 1) {
            ff += __shfl_xor(ff, msk, 64);
            pp += __shfl_xor(pp, msk, 64);
            fp += __shfl_xor(fp, msk, 64);
        }
        acc += 1.0f - fp / (fmaxf(sqrtf(ff), 1e-12f) * fmaxf(sqrtf(pp), 1e-12f));
    }

    __shared__ float s_red[4];
    if (lane == 0) s_red[wave] = acc;
    __syncthreads();
    if (tid == 0)
        partials[blockIdx.x] = s_red[0] + s_red[1] + s_red[2] + s_red[3];
}

// ---------- Kernel C: final reduce ----------
__global__ __launch_bounds__(256) void reduce_partials_kernel(
    const float* __restrict__ partials, int num_partials,
    float* __restrict__ out, float inv_n)
{
    const int tid  = threadIdx.x;
    const int lane = tid & 63;
    const int wave = tid >> 6;
    __shared__ float s_red[4];

    float acc = 0.0f;
    for (int i = tid; i < num_partials; i += 256)
        acc += partials[i];
    #pragma unroll
    for (int msk = 1; msk < 64; msk <<= 1)
        acc += __shfl_xor(acc, msk, 64);
    if (lane == 0) s_red[wave] = acc;
    __syncthreads();
    if (tid == 0)
        out[0] = (s_red[0] + s_red[1] + s_red[2] + s_red[3]) * inv_n;
}

extern "C" void kernel_launch(void* const* d_in, const int* in_sizes, int n_in,
                              void* d_out, int out_size, void* d_ws, size_t ws_size,
                              hipStream_t stream) {
    const float* features   = (const float*)d_in[0];
    const float* labels     = (const float*)d_in[1];
    const float* mean_class = (const float*)d_in[2];
    float* out = (float*)d_out;

    const int n_rows = in_sizes[0] / EMBED;          // 32768
    int* cls_buf    = (int*)d_ws;                    // 128 KB
    float* partials = (float*)d_ws + n_rows;         // 8 KB

    const int dot_blocks = 2048;                     // 8192 waves, 4 rows/wave

    class_scan_kernel<<<n_rows, 256, 0, stream>>>(labels, cls_buf);
    angular_dots_kernel<<<dot_blocks, 256, 0, stream>>>(
        features, mean_class, cls_buf, partials, n_rows);
    reduce_partials_kernel<<<1, 256, 0, stream>>>(
        partials, dot_blocks, out, 1.0f / (float)n_rows);
}